// Round 11
// baseline (201.089 us; speedup 1.0000x reference)
//
#include <hip/hip_runtime.h>
#include <math.h>

// CBAM pillar kernel for MI355X (gfx950) — round 11: SGPR weights.
//
// R10 was LDS-pipe bound: every thread re-streamed ~10KB of weights from
// LDS per pillar (~1.9GB total, ~40us of LDS time) + 3.5M bank conflicts.
// R11: thread-per-pillar => weight addresses are WAVE-UNIFORM; uniform
// loads from const __restrict__ pointers scalarize to s_load (SMEM/K$),
// and v_fma takes an SGPR operand — the weight stream costs ~0 on the
// VALU/LDS/VMEM pipes.  No worker LDS, no barriers.  64-thread blocks
// (pure worker waves).  LDS-transpose epilogue for 1KB-coalesced stores.

#define CO 64

__device__ __forceinline__ float sgm(float x) {
  return 1.0f / (1.0f + __expf(-x));
}

// per-voxel: build packed pillar record pd[p] = {vf0[5], vf1[5], b0, b1}
__global__ __launch_bounds__(256) void pack_kernel(
    const float* __restrict__ vf, const int* __restrict__ vcoord,
    const int* __restrict__ unq_inv, float* __restrict__ pd, int n) {
  int i = blockIdx.x * blockDim.x + threadIdx.x;
  if (i >= n) return;
  int p = unq_inv[i];
  int slot = (i > 0 && unq_inv[i - 1] == p) ? 1 : 0;
  float* dst = pd + 12 * (size_t)p;
#pragma unroll
  for (int k = 0; k < 5; ++k) dst[5 * slot + k] = vf[5 * i + k];
  ((int*)dst)[10 + slot] = vcoord[4 * i + 1];
}

// aux float offsets (within d_ws after pd)
#define A_W1B   0     // 256: [j*8+i] = W1[i][j] (i<5), b1[j] (i==5)
#define A_C0    256   // 64:  c0[ch] = b2 + relu(b1) @ W2
#define A_WSMX  320   // 64:  float2[32] clipped conv-window sums per bin
#define A_WTAB  384   // 16:  float2[8] conv taps, entry 7 = {0,0}
#define A_WC2T  400   // 1024: Wc2 transposed [ch*16 + j]
#define A_SIZE  1424

__global__ __launch_bounds__(256) void aux_kernel(
    const float* __restrict__ W1, const float* __restrict__ b1,
    const float* __restrict__ W2, const float* __restrict__ b2,
    const float* __restrict__ Wc2, const float* __restrict__ Wsp,
    float* __restrict__ aux) {
  const int t = threadIdx.x;
  {
    int j = t >> 3, i = t & 7;
    float v = 0.0f;
    if (i < 5) v = W1[i * 32 + j];
    else if (i == 5) v = b1[j];
    aux[A_W1B + t] = v;
  }
  if (t < 64) {
    float c = b2[t];
    for (int j = 0; j < 32; ++j)
      c += fmaxf(b1[j], 0.0f) * W2[j * 64 + t];
    aux[A_C0 + t] = c;
  }
  if (t < 32) {
    float sm = 0.0f, sx = 0.0f;
    for (int k = 0; k < 7; ++k)
      if ((unsigned)(t + k - 3) < 32u) { sm += Wsp[k]; sx += Wsp[7 + k]; }
    aux[A_WSMX + 2 * t] = sm;
    aux[A_WSMX + 2 * t + 1] = sx;
  }
  if (t < 8) {
    float a = 0.0f, b = 0.0f;
    if (t < 7) { a = Wsp[t]; b = Wsp[7 + t]; }
    aux[A_WTAB + 2 * t] = a;
    aux[A_WTAB + 2 * t + 1] = b;
  }
  for (int i = t; i < 1024; i += 256)
    aux[A_WC2T + i] = Wc2[(i & 15) * 64 + (i >> 4)];
}

__global__ __launch_bounds__(64) void cbam_kernel(
    const float4* __restrict__ pdv, const int* __restrict__ unq_cnt,
    const float* __restrict__ W2, const float* __restrict__ b2,
    const float* __restrict__ Wc1, const float* __restrict__ bc1,
    const float* __restrict__ bc2, const float* __restrict__ bsp,
    const float* __restrict__ aux, float* __restrict__ out, int U) {
  const int tid = threadIdx.x;               // 0..63, one wave per block
  const int p = blockIdx.x * 64 + tid;
  const int pc = p < U ? p : (U - 1);
  __shared__ float T[64 * 65];               // store-transpose buffer

  // ---- per-lane pillar record (coalesced vector loads)
  const float4 A  = pdv[3 * (size_t)pc];
  const float4 B  = pdv[3 * (size_t)pc + 1];
  const float4 Cq = pdv[3 * (size_t)pc + 2];
  const int cnt = unq_cnt[pc];
  const bool has2 = (cnt >= 2);
  float vf0[5] = {A.x, A.y, A.z, A.w, B.x};
  float vf1[5] = {B.y, B.z, B.w, Cq.x, Cq.y};
#pragma unroll
  for (int i = 0; i < 5; ++i) vf1[i] = has2 ? vf1[i] : vf0[i];
  const int b0  = __builtin_bit_cast(int, Cq.z) & 31;
  const int b1e = has2 ? (__builtin_bit_cast(int, Cq.w) & 31) : 64;

  const float4* aux4 = (const float4*)aux;   // uniform -> s_load
  const float4* b24  = (const float4*)b2;
  const float4* w24  = (const float4*)W2;
  const float4* wc14 = (const float4*)Wc1;
  const float4* bc14 = (const float4*)bc1;
  const float4* bc24 = (const float4*)bc2;

  // ---- up-dimension MLP: y0/y1[64] in registers, weights via SGPRs
  float y0[64], y1[64];
#pragma unroll
  for (int cb = 0; cb < 16; ++cb) {
    float4 bb = b24[cb];
    y0[4 * cb] = bb.x; y0[4 * cb + 1] = bb.y;
    y0[4 * cb + 2] = bb.z; y0[4 * cb + 3] = bb.w;
    y1[4 * cb] = bb.x; y1[4 * cb + 1] = bb.y;
    y1[4 * cb + 2] = bb.z; y1[4 * cb + 3] = bb.w;
  }
  for (int j = 0; j < 32; ++j) {
    float4 wA = aux4[A_W1B / 4 + 2 * j];
    float4 wB = aux4[A_W1B / 4 + 2 * j + 1];
    float h0 = wB.y + vf0[0] * wA.x + vf0[1] * wA.y + vf0[2] * wA.z +
               vf0[3] * wA.w + vf0[4] * wB.x;
    float h1 = wB.y + vf1[0] * wA.x + vf1[1] * wA.y + vf1[2] * wA.z +
               vf1[3] * wA.w + vf1[4] * wB.x;
    h0 = fmaxf(h0, 0.0f);
    h1 = fmaxf(h1, 0.0f);
#pragma unroll
    for (int cb = 0; cb < 16; ++cb) {
      float4 w = w24[j * 16 + cb];           // uniform -> SGPR
      y0[4 * cb]     += h0 * w.x; y0[4 * cb + 1] += h0 * w.y;
      y0[4 * cb + 2] += h0 * w.z; y0[4 * cb + 3] += h0 * w.w;
      y1[4 * cb]     += h1 * w.x; y1[4 * cb + 1] += h1 * w.y;
      y1[4 * cb + 2] += h1 * w.z; y1[4 * cb + 3] += h1 * w.w;
    }
  }

  // ---- pooled stats + channel-MLP layer 1 (streamed)
  float ha[16], hm[16];
#pragma unroll
  for (int jb = 0; jb < 4; ++jb) {
    float4 bb = bc14[jb];
    ha[4 * jb] = bb.x; ha[4 * jb + 1] = bb.y;
    ha[4 * jb + 2] = bb.z; ha[4 * jb + 3] = bb.w;
    hm[4 * jb] = bb.x; hm[4 * jb + 1] = bb.y;
    hm[4 * jb + 2] = bb.z; hm[4 * jb + 3] = bb.w;
  }
  const float kf = has2 ? 30.0f : 31.0f;     // 32 - nocc
  const float inv32 = 1.0f / 32.0f;
#pragma unroll
  for (int cb = 0; cb < 16; ++cb) {
    float4 c0q = aux4[A_C0 / 4 + cb];
    float c0a[4] = {c0q.x, c0q.y, c0q.z, c0q.w};
#pragma unroll
    for (int i = 0; i < 4; ++i) {
      int ch = 4 * cb + i;
      float c0v = c0a[i];
      float y1s = has2 ? y1[ch] : 0.0f;
      float sumy = y0[ch] + y1s;
      float maxy = fmaxf(y0[ch], y1[ch]);
      float avg = fmaf(c0v, kf, sumy) * inv32;
      float mxv = fmaxf(maxy, c0v);
#pragma unroll
      for (int jb = 0; jb < 4; ++jb) {
        float4 w = wc14[ch * 4 + jb];        // uniform -> SGPR
        ha[4 * jb]     += avg * w.x; ha[4 * jb + 1] += avg * w.y;
        ha[4 * jb + 2] += avg * w.z; ha[4 * jb + 3] += avg * w.w;
        hm[4 * jb]     += mxv * w.x; hm[4 * jb + 1] += mxv * w.y;
        hm[4 * jb + 2] += mxv * w.z; hm[4 * jb + 3] += mxv * w.w;
      }
    }
  }
  float g[16];
#pragma unroll
  for (int j = 0; j < 16; ++j)
    g[j] = fmaxf(ha[j], 0.0f) + fmaxf(hm[j], 0.0f);

  // ---- channel attention + bin-column reductions (attc recomputed later)
  float sc = 0.0f, mc = -3.0e38f;
  float sy0 = 0.0f, my0 = -3.0e38f, sy1 = 0.0f, my1 = -3.0e38f;
#pragma unroll
  for (int cb = 0; cb < 16; ++cb) {
    float4 c0q  = aux4[A_C0 / 4 + cb];
    float4 bq   = bc24[cb];
    float c0a[4] = {c0q.x, c0q.y, c0q.z, c0q.w};
    float b2a[4] = {bq.x, bq.y, bq.z, bq.w};
#pragma unroll
    for (int i = 0; i < 4; ++i) {
      int ch = 4 * cb + i;
      float4 wa = aux4[A_WC2T / 4 + ch * 4 + 0];
      float4 wb = aux4[A_WC2T / 4 + ch * 4 + 1];
      float4 wc = aux4[A_WC2T / 4 + ch * 4 + 2];
      float4 wd = aux4[A_WC2T / 4 + ch * 4 + 3];
      float q0 = g[0] * wa.x + g[1] * wa.y + g[2] * wa.z + g[3] * wa.w;
      float q1 = g[4] * wb.x + g[5] * wb.y + g[6] * wb.z + g[7] * wb.w;
      float q2 = g[8] * wc.x + g[9] * wc.y + g[10] * wc.z + g[11] * wc.w;
      float q3 = g[12] * wd.x + g[13] * wd.y + g[14] * wd.z + g[15] * wd.w;
      float pre = 2.0f * b2a[i] + (q0 + q1) + (q2 + q3);
      float a = sgm(pre);
      float c0v = c0a[i];
      float pc0 = a * c0v, py0 = a * y0[ch], py1 = a * y1[ch];
      sc += pc0;  mc = fmaxf(mc, pc0);
      sy0 += py0; my0 = fmaxf(my0, py0);
      sy1 += py1; my1 = fmaxf(my1, py1);
    }
  }

  // ---- analytic bin-attention conv over 32 bins (uniform loop)
  const float inv64 = 1.0f / 64.0f;
  const float Mn = sc * inv64, Mx = mc;
  const float dm0 = (sy0 - sc) * inv64, dx0 = my0 - mc;
  const float dm1 = (sy1 - sc) * inv64, dx1 = my1 - mc;
  const float bspr = bsp[0];
  const float2* Lws = (const float2*)(aux + A_WSMX);
  const float2* Lwt = (const float2*)(aux + A_WTAB);
  float maxE = -3.0e38f, minE = 3.0e38f, sv0 = 0.0f, sv1 = 0.0f;
  for (int b = 0; b < 32; ++b) {
    float2 ws = Lws[b];                      // uniform -> SGPR
    float acc = bspr + Mn * ws.x + Mx * ws.y;
    int k0 = b0 - b + 3;  k0 = ((unsigned)k0 <= 6u) ? k0 : 7;
    int k1 = b1e - b + 3; k1 = ((unsigned)k1 <= 6u) ? k1 : 7;
    float2 w0 = Lwt[k0];                     // lane-varying, 64B L1-hot
    float2 w1v = Lwt[k1];
    acc += dm0 * w0.x + dx0 * w0.y + dm1 * w1v.x + dx1 * w1v.y;
    bool o0 = (b == b0), o1 = (b == b1e);
    bool oc = o0 || o1;
    maxE = fmaxf(maxE, oc ? -3.0e38f : acc);
    minE = fminf(minE, oc ?  3.0e38f : acc);
    sv0 = o0 ? acc : sv0;
    sv1 = o1 ? acc : sv1;
  }
  const float sig0 = sgm(sv0);
  const float sig1 = has2 ? sgm(sv1) : sig0;
  const float sEv = sgm(maxE), sIv = sgm(minE);

  // ---- epilogue: recompute attc, final max, LDS transpose
#pragma unroll
  for (int cb = 0; cb < 16; ++cb) {
    float4 c0q = aux4[A_C0 / 4 + cb];
    float4 bq  = bc24[cb];
    float c0a[4] = {c0q.x, c0q.y, c0q.z, c0q.w};
    float b2a[4] = {bq.x, bq.y, bq.z, bq.w};
#pragma unroll
    for (int i = 0; i < 4; ++i) {
      int ch = 4 * cb + i;
      float4 wa = aux4[A_WC2T / 4 + ch * 4 + 0];
      float4 wb = aux4[A_WC2T / 4 + ch * 4 + 1];
      float4 wc = aux4[A_WC2T / 4 + ch * 4 + 2];
      float4 wd = aux4[A_WC2T / 4 + ch * 4 + 3];
      float q0 = g[0] * wa.x + g[1] * wa.y + g[2] * wa.z + g[3] * wa.w;
      float q1 = g[4] * wb.x + g[5] * wb.y + g[6] * wb.z + g[7] * wb.w;
      float q2 = g[8] * wc.x + g[9] * wc.y + g[10] * wc.z + g[11] * wc.w;
      float q3 = g[12] * wd.x + g[13] * wd.y + g[14] * wd.z + g[15] * wd.w;
      float pre = 2.0f * b2a[i] + (q0 + q1) + (q2 + q3);
      float attc = sgm(pre);
      float c0v = c0a[i];
      float sel = (c0v >= 0.0f) ? sEv : sIv;
      float m = fmaxf(fmaxf(y0[ch] * sig0, y1[ch] * sig1), c0v * sel);
      T[tid * 65 + ch] = attc * m;           // bank (tid+ch)%32: 2-way, free
    }
  }
  __builtin_amdgcn_wave_barrier();
  __builtin_amdgcn_s_waitcnt(0xC07F);        // lgkmcnt(0)
  __builtin_amdgcn_wave_barrier();

  // coalesced stores: 4 rows (1KB contiguous) per instruction
  const int r4 = tid >> 4;                   // row within group of 4
  const int cc = tid & 15;                   // float4 index within row
  float4* outv = (float4*)out;
#pragma unroll
  for (int i = 0; i < 16; ++i) {
    int row = 4 * i + r4;
    int pr = blockIdx.x * 64 + row;
    if (pr < U) {
      float4 v;
      v.x = T[row * 65 + 4 * cc + 0];
      v.y = T[row * 65 + 4 * cc + 1];
      v.z = T[row * 65 + 4 * cc + 2];
      v.w = T[row * 65 + 4 * cc + 3];
      outv[(size_t)pr * 16 + cc] = v;
    }
  }
  if (p < U) out[(size_t)U * CO + p] = has2 ? 1.0f : 0.0f;
}

extern "C" void kernel_launch(void* const* d_in, const int* in_sizes, int n_in,
                              void* d_out, int out_size, void* d_ws, size_t ws_size,
                              hipStream_t stream) {
  const float* vf      = (const float*)d_in[0];
  const int*   vcoord  = (const int*)d_in[1];
  // d_in[2] = unq_coords (unused: identity)
  const int*   unq_inv = (const int*)d_in[3];
  const int*   unq_cnt = (const int*)d_in[4];
  const float* W1  = (const float*)d_in[5];
  const float* b1  = (const float*)d_in[6];
  const float* W2  = (const float*)d_in[7];
  const float* b2  = (const float*)d_in[8];
  const float* Wc1 = (const float*)d_in[9];
  const float* bc1 = (const float*)d_in[10];
  const float* Wc2 = (const float*)d_in[11];
  const float* bc2 = (const float*)d_in[12];
  const float* Wsp = (const float*)d_in[13];
  const float* bsp = (const float*)d_in[14];

  const int N = in_sizes[3];   // voxels
  const int U = in_sizes[4];   // pillars

  float* pd  = (float*)d_ws;           // 12 floats per pillar
  float* aux = pd + 12 * (size_t)U;    // A_SIZE floats (16B-aligned: 48U%16==0)

  pack_kernel<<<(N + 255) / 256, 256, 0, stream>>>(vf, vcoord, unq_inv, pd, N);
  aux_kernel<<<1, 256, 0, stream>>>(W1, b1, W2, b2, Wc2, Wsp, aux);

  const int blocks = (U + 63) / 64;    // one THREAD per pillar, 1-wave blocks
  cbam_kernel<<<blocks, 64, 0, stream>>>(
      (const float4*)pd, unq_cnt, W2, b2, Wc1, bc1, bc2, bsp, aux,
      (float*)d_out, U);
}

// Round 12
// 155.497 us; speedup vs baseline: 1.2932x; 1.2932x over previous
//
#include <hip/hip_runtime.h>
#include <math.h>

// CBAM pillar kernel for MI355X (gfx950) — round 12: phase-switch,
// 4 threads per pillar, quad-DPP reductions.
//
// Evidence synthesis R1-R11: wave-per-pillar floors at ~2200cy/pillar on
// cross-lane chains; thread-per-pillar floors on grid size (1563 waves) /
// spills; 2-thread floors on LDS weight streaming.  R12: wave = 16 pillars.
// Phase 1 (lane=(j,vox-half)): layer1, W1 in VGPRs, h -> LDS (ONE drain).
// Phase 2 (lane=(pillar, ch-quad)): per-thread 16-channel slice; layer2
// reads h broadcast + W2 from padded block-LDS; pooling/chMLP/conv all
// thread-local; cross-lane = 2-instr quad_perm DPP reductions only.
// 6250 waves, no 64-lane butterflies, no readlane chains, no transposes.

#define CO 64

__device__ __forceinline__ float sgm(float x) {
  return 1.0f / (1.0f + __expf(-x));
}
template <int PAT>
__device__ __forceinline__ float qadd(float s) {
  int t = __builtin_amdgcn_update_dpp(0, __builtin_bit_cast(int, s),
                                      PAT, 0xf, 0xf, true);
  return s + __builtin_bit_cast(float, t);
}
template <int PAT>
__device__ __forceinline__ float qmaxd(float m) {
  int t = __builtin_amdgcn_update_dpp(__builtin_bit_cast(int, m),
                                      __builtin_bit_cast(int, m),
                                      PAT, 0xf, 0xf, false);
  return fmaxf(m, __builtin_bit_cast(float, t));
}
template <int PAT>
__device__ __forceinline__ float qmind(float m) {
  int t = __builtin_amdgcn_update_dpp(__builtin_bit_cast(int, m),
                                      __builtin_bit_cast(int, m),
                                      PAT, 0xf, 0xf, false);
  return fminf(m, __builtin_bit_cast(float, t));
}
// full exchange within each 4-lane quad: 0xB1=[1,0,3,2], 0x4E=[2,3,0,1]
__device__ __forceinline__ float qsum4(float s) { return qadd<0x4E>(qadd<0xB1>(s)); }
__device__ __forceinline__ float qmax4(float m) { return qmaxd<0x4E>(qmaxd<0xB1>(m)); }
__device__ __forceinline__ float qmin4(float m) { return qmind<0x4E>(qmind<0xB1>(m)); }
__device__ __forceinline__ void drain_lds() {
  __builtin_amdgcn_wave_barrier();
  __builtin_amdgcn_s_waitcnt(0xC07F);   // lgkmcnt(0)
  __builtin_amdgcn_wave_barrier();
}

// per-voxel: pvox[2p+slot] = {vf[5], bits(bin), 0, 0}  (32B records)
__global__ __launch_bounds__(256) void pack_kernel(
    const float* __restrict__ vf, const int* __restrict__ vcoord,
    const int* __restrict__ unq_inv, float* __restrict__ pvox, int n) {
  int i = blockIdx.x * blockDim.x + threadIdx.x;
  if (i >= n) return;
  int p = unq_inv[i];
  int slot = (i > 0 && unq_inv[i - 1] == p) ? 1 : 0;
  float* dst = pvox + 8 * (size_t)(2 * p + slot);
#pragma unroll
  for (int k = 0; k < 5; ++k) dst[k] = vf[5 * i + k];
  ((int*)dst)[5] = vcoord[4 * i + 1];
}

__global__ __launch_bounds__(256) void cbam_kernel(
    const float* __restrict__ pvox, const int* __restrict__ unq_cnt,
    const float* __restrict__ W1, const float* __restrict__ b1,
    const float* __restrict__ W2, const float* __restrict__ b2,
    const float* __restrict__ Wc1, const float* __restrict__ bc1,
    const float* __restrict__ Wc2, const float* __restrict__ bc2,
    const float* __restrict__ Wsp, const float* __restrict__ bsp,
    float* __restrict__ out, int U) {
  __shared__ __align__(16) float w2b[2176];   // 32 rows, stride 68 (pad)
  __shared__ __align__(16) float wc1b[1024];  // [ch*16+j]
  __shared__ __align__(16) float wc2b[1024];  // Wc2^T [ch*16+j]
  __shared__ __align__(16) float c0b[64], b2b[64], bc2b[64], bc1b[16];
  __shared__ __align__(16) float wsmx[64];    // float2[32] window sums
  __shared__ __align__(16) float wtab[16];    // float2[8] taps, [7]={0,0}
  __shared__ __align__(16) float hbuf[4][1152];  // per-wave 32 x stride 36

  const int tid = threadIdx.x;

  // ---- stage weights to LDS (once per block)
  for (int i = tid; i < 2048; i += 256) w2b[(i >> 6) * 68 + (i & 63)] = W2[i];
  for (int i = tid; i < 1024; i += 256) wc1b[i] = Wc1[i];
  for (int i = tid; i < 1024; i += 256) wc2b[i] = Wc2[(i & 15) * 64 + (i >> 4)];
  if (tid < 64) { b2b[tid] = b2[tid]; bc2b[tid] = bc2[tid]; }
  if (tid < 16) bc1b[tid] = bc1[tid];
  if (tid < 32) {
    float sm = 0.0f, sx = 0.0f;
    for (int k = 0; k < 7; ++k)
      if ((unsigned)(tid + k - 3) < 32u) { sm += Wsp[k]; sx += Wsp[7 + k]; }
    wsmx[2 * tid] = sm; wsmx[2 * tid + 1] = sx;
  }
  if (tid < 8) {
    float a = 0.0f, b = 0.0f;
    if (tid < 7) { a = Wsp[tid]; b = Wsp[7 + tid]; }
    wtab[2 * tid] = a; wtab[2 * tid + 1] = b;
  }
  __syncthreads();
  if (tid < 64) {                      // c0[ch] = b2 + relu(b1) @ W2
    float c = b2b[tid];
    for (int j = 0; j < 32; ++j) c += fmaxf(b1[j], 0.0f) * w2b[j * 68 + tid];
    c0b[tid] = c;
  }
  __syncthreads();

  const int wv = tid >> 6, lane = tid & 63;
  const int P0 = (blockIdx.x * 4 + wv) * 16;     // 16 pillars per wave
  if (P0 >= U) return;
  float* const hb = hbuf[wv];

  // ---- phase 1: layer1.  lane = (j = lane&31, voxel-half = lane>>5)
  {
    const int j32 = lane & 31, vh = lane >> 5;
    float w1r[5];
#pragma unroll
    for (int i = 0; i < 5; ++i) w1r[i] = W1[i * 32 + j32];
    const float b1r = b1[j32];
    const float4* pv4 = (const float4*)pvox;
    const int vmax = 2 * U - 1;
#pragma unroll
    for (int v = 0; v < 16; ++v) {
      int vg = 2 * P0 + 16 * vh + v;
      vg = vg < vmax ? vg : vmax;
      float4 g1 = pv4[2 * vg];
      float4 g2 = pv4[2 * vg + 1];
      float h = b1r + g1.x * w1r[0] + g1.y * w1r[1] + g1.z * w1r[2] +
                g1.w * w1r[3] + g2.x * w1r[4];
      hb[(16 * vh + v) * 36 + j32] = fmaxf(h, 0.0f);
    }
  }
  drain_lds();

  // ---- phase 2: lane = (pillar pp = lane>>2, ch-quad q = lane&3)
  const int q = lane & 3, pp = lane >> 2;
  const int pg = P0 + pp;
  const int pc = pg < U ? pg : (U - 1);
  const int cnt = unq_cnt[pc];
  const bool has2 = (cnt >= 2);
  const int* pvi = (const int*)pvox;
  const int b0 = pvi[(size_t)(2 * pc) * 8 + 5] & 31;
  const int b1raw = pvi[(size_t)(2 * pc + 1) * 8 + 5];
  const int b1e = has2 ? (b1raw & 31) : 64;

  // layer2: this thread's 16 channels (16q..16q+15), both voxels
  float y0[16], y1[16];
  const float4* b2b4 = (const float4*)b2b;
#pragma unroll
  for (int kb = 0; kb < 4; ++kb) {
    float4 w = b2b4[q * 4 + kb];
    y0[4 * kb] = w.x; y0[4 * kb + 1] = w.y; y0[4 * kb + 2] = w.z; y0[4 * kb + 3] = w.w;
    y1[4 * kb] = w.x; y1[4 * kb + 1] = w.y; y1[4 * kb + 2] = w.z; y1[4 * kb + 3] = w.w;
  }
  const float4* hb4 = (const float4*)hb;
  const float4* w2b4 = (const float4*)w2b;
#pragma unroll
  for (int jb = 0; jb < 8; ++jb) {
    float4 h0 = hb4[(2 * pp) * 9 + jb];        // broadcast-ish reads
    float4 h1 = hb4[(2 * pp + 1) * 9 + jb];
    float h0a[4] = {h0.x, h0.y, h0.z, h0.w};
    float h1a[4] = {h1.x, h1.y, h1.z, h1.w};
#pragma unroll
    for (int jj = 0; jj < 4; ++jj) {
      const int j = 4 * jb + jj;
#pragma unroll
      for (int kb = 0; kb < 4; ++kb) {
        float4 w = w2b4[17 * j + 4 * q + kb];  // stride-68 pad: ~2-way
        y0[4 * kb]     += h0a[jj] * w.x; y0[4 * kb + 1] += h0a[jj] * w.y;
        y0[4 * kb + 2] += h0a[jj] * w.z; y0[4 * kb + 3] += h0a[jj] * w.w;
        y1[4 * kb]     += h1a[jj] * w.x; y1[4 * kb + 1] += h1a[jj] * w.y;
        y1[4 * kb + 2] += h1a[jj] * w.z; y1[4 * kb + 3] += h1a[jj] * w.w;
      }
    }
  }
#pragma unroll
  for (int k = 0; k < 16; ++k) y1[k] = has2 ? y1[k] : y0[k];  // mask garbage

  // pooled stats + chMLP layer1 partials (thread-local over 16 ch)
  float ha[16] = {0}, hm[16] = {0};
  const float kf = has2 ? 30.0f : 31.0f;       // 32 - nocc
  const float inv32 = 1.0f / 32.0f;
  const float4* c04 = (const float4*)c0b;
  const float4* wc14 = (const float4*)wc1b;
#pragma unroll
  for (int kb = 0; kb < 4; ++kb) {
    float4 cq = c04[q * 4 + kb];
    float c0a[4] = {cq.x, cq.y, cq.z, cq.w};
#pragma unroll
    for (int i = 0; i < 4; ++i) {
      const int k = 4 * kb + i;
      const float c0v = c0a[i];
      const float sumy = y0[k] + (has2 ? y1[k] : 0.0f);
      const float avg = fmaf(c0v, kf, sumy) * inv32;
      const float mxv = fmaxf(fmaxf(y0[k], y1[k]), c0v);
#pragma unroll
      for (int jb = 0; jb < 4; ++jb) {
        float4 w = wc14[(16 * q + k) * 4 + jb];
        ha[4 * jb]     += avg * w.x; ha[4 * jb + 1] += avg * w.y;
        ha[4 * jb + 2] += avg * w.z; ha[4 * jb + 3] += avg * w.w;
        hm[4 * jb]     += mxv * w.x; hm[4 * jb + 1] += mxv * w.y;
        hm[4 * jb + 2] += mxv * w.z; hm[4 * jb + 3] += mxv * w.w;
      }
    }
  }
  // quad-reduce partials (full 64-ch sums), bias, relu, combine pools
  float g[16];
  const float4* bc14 = (const float4*)bc1b;
#pragma unroll
  for (int jb = 0; jb < 4; ++jb) {
    float4 bb = bc14[jb];
    float bba[4] = {bb.x, bb.y, bb.z, bb.w};
#pragma unroll
    for (int i = 0; i < 4; ++i) {
      const int j = 4 * jb + i;
      const float sa = qsum4(ha[j]) + bba[i];
      const float sm = qsum4(hm[j]) + bba[i];
      g[j] = fmaxf(sa, 0.0f) + fmaxf(sm, 0.0f);
    }
  }

  // chMLP layer2 -> attc; bin-column partial reductions
  float attc[16];
  float sc = 0.0f, mc = -3.0e38f;
  float sy0 = 0.0f, my0 = -3.0e38f, sy1 = 0.0f, my1 = -3.0e38f;
  const float4* wc24 = (const float4*)wc2b;
  const float4* bc24 = (const float4*)bc2b;
#pragma unroll
  for (int kb = 0; kb < 4; ++kb) {
    float4 cq = c04[q * 4 + kb];
    float4 bq = bc24[q * 4 + kb];
    float c0a[4] = {cq.x, cq.y, cq.z, cq.w};
    float b2a[4] = {bq.x, bq.y, bq.z, bq.w};
#pragma unroll
    for (int i = 0; i < 4; ++i) {
      const int k = 4 * kb + i;
      float pre = 2.0f * b2a[i];
#pragma unroll
      for (int jb = 0; jb < 4; ++jb) {
        float4 w = wc24[(16 * q + k) * 4 + jb];
        pre += g[4 * jb] * w.x + g[4 * jb + 1] * w.y +
               g[4 * jb + 2] * w.z + g[4 * jb + 3] * w.w;
      }
      const float a = sgm(pre);
      attc[k] = a;
      const float pc0 = a * c0a[i], py0 = a * y0[k], py1 = a * y1[k];
      sc += pc0;  mc = fmaxf(mc, pc0);
      sy0 += py0; my0 = fmaxf(my0, py0);
      sy1 += py1; my1 = fmaxf(my1, py1);
    }
  }
  sc = qsum4(sc);   mc = qmax4(mc);
  sy0 = qsum4(sy0); my0 = qmax4(my0);
  sy1 = qsum4(sy1); my1 = qmax4(my1);

  // analytic conv over 32 bins, 8 bins per lane, quad-combined
  const float inv64 = 1.0f / 64.0f;
  const float Mn = sc * inv64, Mx = mc;
  const float dm0 = (sy0 - sc) * inv64, dx0 = my0 - mc;
  const float dm1 = (sy1 - sc) * inv64, dx1 = my1 - mc;
  const float bspr = bsp[0];
  const float2* ws2 = (const float2*)wsmx;
  const float2* wt2 = (const float2*)wtab;
  float maxE = -3.0e38f, minE = 3.0e38f, sv0 = -3.0e38f, sv1 = -3.0e38f;
#pragma unroll
  for (int k = 0; k < 8; ++k) {
    const int b = 8 * q + k;
    float2 ws = ws2[b];
    float acc = bspr + Mn * ws.x + Mx * ws.y;
    int k0 = b0 - b + 3;  k0 = ((unsigned)k0 <= 6u) ? k0 : 7;
    int k1 = b1e - b + 3; k1 = ((unsigned)k1 <= 6u) ? k1 : 7;
    float2 w0 = wt2[k0];
    float2 w1v = wt2[k1];
    acc += dm0 * w0.x + dx0 * w0.y + dm1 * w1v.x + dx1 * w1v.y;
    const bool o0 = (b == b0), o1 = (b == b1e);
    const bool oc = o0 || o1;
    maxE = fmaxf(maxE, oc ? -3.0e38f : acc);
    minE = fminf(minE, oc ?  3.0e38f : acc);
    sv0 = o0 ? acc : sv0;
    sv1 = o1 ? acc : sv1;
  }
  maxE = qmax4(maxE); minE = qmin4(minE);
  sv0 = qmax4(sv0);   sv1 = qmax4(sv1);
  const float sig0 = sgm(sv0);
  const float sig1 = has2 ? sgm(sv1) : sig0;
  const float sE = sgm(maxE), sI = sgm(minE);

  // epilogue: final max over bins, coalesced stores (1KB per instr)
  if (pg < U) {
    float4* ov = (float4*)(out + (size_t)pg * CO + 16 * q);
#pragma unroll
    for (int kb = 0; kb < 4; ++kb) {
      float4 cq = c04[q * 4 + kb];
      float c0a[4] = {cq.x, cq.y, cq.z, cq.w};
      float rr[4];
#pragma unroll
      for (int i = 0; i < 4; ++i) {
        const int k = 4 * kb + i;
        const float c0v = c0a[i];
        const float sel = (c0v >= 0.0f) ? sE : sI;
        const float m = fmaxf(fmaxf(y0[k] * sig0, y1[k] * sig1), c0v * sel);
        rr[i] = attc[k] * m;
      }
      float4 r; r.x = rr[0]; r.y = rr[1]; r.z = rr[2]; r.w = rr[3];
      ov[kb] = r;
    }
    if (q == 0) out[(size_t)U * CO + pg] = has2 ? 1.0f : 0.0f;
  }
}

extern "C" void kernel_launch(void* const* d_in, const int* in_sizes, int n_in,
                              void* d_out, int out_size, void* d_ws, size_t ws_size,
                              hipStream_t stream) {
  const float* vf      = (const float*)d_in[0];
  const int*   vcoord  = (const int*)d_in[1];
  // d_in[2] = unq_coords (unused: identity)
  const int*   unq_inv = (const int*)d_in[3];
  const int*   unq_cnt = (const int*)d_in[4];
  const float* W1  = (const float*)d_in[5];
  const float* b1  = (const float*)d_in[6];
  const float* W2  = (const float*)d_in[7];
  const float* b2  = (const float*)d_in[8];
  const float* Wc1 = (const float*)d_in[9];
  const float* bc1 = (const float*)d_in[10];
  const float* Wc2 = (const float*)d_in[11];
  const float* bc2 = (const float*)d_in[12];
  const float* Wsp = (const float*)d_in[13];
  const float* bsp = (const float*)d_in[14];

  const int N = in_sizes[3];   // voxels
  const int U = in_sizes[4];   // pillars

  float* pvox = (float*)d_ws;  // 2U records x 32B (6.4 MB @ U=100k)

  pack_kernel<<<(N + 255) / 256, 256, 0, stream>>>(vf, vcoord, unq_inv, pvox, N);

  const int waves = (U + 15) / 16;        // 16 pillars per wave
  const int blocks = (waves + 3) / 4;     // 4 waves per block
  cbam_kernel<<<blocks, 256, 0, stream>>>(
      pvox, unq_cnt, W1, b1, W2, b2, Wc1, bc1, Wc2, bc2, Wsp, bsp,
      (float*)d_out, U);
}

// Round 13
// 147.592 us; speedup vs baseline: 1.3625x; 1.0536x over previous
//
#include <hip/hip_runtime.h>
#include <math.h>

// CBAM pillar kernel for MI355X (gfx950) — round 13.
//
// R12 (72us) left: 10M LDS bank conflicts (h reads bank-step 8 -> 4-way;
// wc1/wc2 q-blocks bank-aligned -> 4-way), 17% occupancy (1563 short
// blocks, staging prologue each), stall-dominated VALU 50%.
// R13: (a) conflict-free layouts: hbuf rows (slot*16+pp) -> h-read bank
// step 4 (2-way=free); wc1/wc2 k-major (4k+q)*16+j -> q addrs 16 banks
// apart (2-way=free); (b) persistent 1024-block grid (4 blocks/CU
// resident), wave-level trip loop, no in-loop __syncthreads;
// (c) 2-deep h read-ahead in layer2.

#define CO 64

__device__ __forceinline__ float sgm(float x) {
  return 1.0f / (1.0f + __expf(-x));
}
template <int PAT>
__device__ __forceinline__ float qadd(float s) {
  int t = __builtin_amdgcn_update_dpp(0, __builtin_bit_cast(int, s),
                                      PAT, 0xf, 0xf, true);
  return s + __builtin_bit_cast(float, t);
}
template <int PAT>
__device__ __forceinline__ float qmaxd(float m) {
  int t = __builtin_amdgcn_update_dpp(__builtin_bit_cast(int, m),
                                      __builtin_bit_cast(int, m),
                                      PAT, 0xf, 0xf, false);
  return fmaxf(m, __builtin_bit_cast(float, t));
}
template <int PAT>
__device__ __forceinline__ float qmind(float m) {
  int t = __builtin_amdgcn_update_dpp(__builtin_bit_cast(int, m),
                                      __builtin_bit_cast(int, m),
                                      PAT, 0xf, 0xf, false);
  return fminf(m, __builtin_bit_cast(float, t));
}
// full exchange within each 4-lane quad: 0xB1=[1,0,3,2], 0x4E=[2,3,0,1]
__device__ __forceinline__ float qsum4(float s) { return qadd<0x4E>(qadd<0xB1>(s)); }
__device__ __forceinline__ float qmax4(float m) { return qmaxd<0x4E>(qmaxd<0xB1>(m)); }
__device__ __forceinline__ float qmin4(float m) { return qmind<0x4E>(qmind<0xB1>(m)); }
__device__ __forceinline__ void drain_lds() {
  __builtin_amdgcn_wave_barrier();
  __builtin_amdgcn_s_waitcnt(0xC07F);   // lgkmcnt(0)
  __builtin_amdgcn_wave_barrier();
}

// per-voxel: pvox[2p+slot] = {vf[5], bits(bin), 0, 0}  (32B records)
__global__ __launch_bounds__(256) void pack_kernel(
    const float* __restrict__ vf, const int* __restrict__ vcoord,
    const int* __restrict__ unq_inv, float* __restrict__ pvox, int n) {
  int i = blockIdx.x * blockDim.x + threadIdx.x;
  if (i >= n) return;
  int p = unq_inv[i];
  int slot = (i > 0 && unq_inv[i - 1] == p) ? 1 : 0;
  float* dst = pvox + 8 * (size_t)(2 * p + slot);
#pragma unroll
  for (int k = 0; k < 5; ++k) dst[k] = vf[5 * i + k];
  ((int*)dst)[5] = vcoord[4 * i + 1];
}

__global__ __launch_bounds__(256) void cbam_kernel(
    const float* __restrict__ pvox, const int* __restrict__ unq_cnt,
    const float* __restrict__ W1, const float* __restrict__ b1,
    const float* __restrict__ W2, const float* __restrict__ b2,
    const float* __restrict__ Wc1, const float* __restrict__ bc1,
    const float* __restrict__ Wc2, const float* __restrict__ bc2,
    const float* __restrict__ Wsp, const float* __restrict__ bsp,
    float* __restrict__ out, int U, int ngroups, int totalWaves) {
  __shared__ __align__(16) float w2b[2176];   // 32 rows, stride 68 (pad)
  __shared__ __align__(16) float wc1b[1024];  // k-major: [(4k+q)*16 + j]
  __shared__ __align__(16) float wc2b[1024];  // k-major Wc2^T
  __shared__ __align__(16) float c0b[64], b2b[64], bc2b[64], bc1b[16];
  __shared__ __align__(16) float wsmx[64];    // float2[32] window sums
  __shared__ __align__(16) float wtab[16];    // float2[8] taps, [7]={0,0}
  __shared__ __align__(16) float hbuf[4][1152];  // per-wave 32 x stride 36

  const int tid = threadIdx.x;

  // ---- stage weights to LDS (once per block; persistent blocks)
  for (int i = tid; i < 2048; i += 256) w2b[(i >> 6) * 68 + (i & 63)] = W2[i];
  for (int i = tid; i < 1024; i += 256) {
    // i = ch*16 + j, ch = 16q + k  ->  dst (4k+q)*16 + j
    int ch = i >> 4, j = i & 15, qq = ch >> 4, k = ch & 15;
    wc1b[(4 * k + qq) * 16 + j] = Wc1[i];
    wc2b[(4 * k + qq) * 16 + j] = Wc2[j * 64 + ch];
  }
  if (tid < 64) { b2b[tid] = b2[tid]; bc2b[tid] = bc2[tid]; }
  if (tid < 16) bc1b[tid] = bc1[tid];
  if (tid < 32) {
    float sm = 0.0f, sx = 0.0f;
    for (int k = 0; k < 7; ++k)
      if ((unsigned)(tid + k - 3) < 32u) { sm += Wsp[k]; sx += Wsp[7 + k]; }
    wsmx[2 * tid] = sm; wsmx[2 * tid + 1] = sx;
  }
  if (tid < 8) {
    float a = 0.0f, b = 0.0f;
    if (tid < 7) { a = Wsp[tid]; b = Wsp[7 + tid]; }
    wtab[2 * tid] = a; wtab[2 * tid + 1] = b;
  }
  __syncthreads();
  if (tid < 64) {                      // c0[ch] = b2 + relu(b1) @ W2
    float c = b2b[tid];
    for (int j = 0; j < 32; ++j) c += fmaxf(b1[j], 0.0f) * w2b[j * 68 + tid];
    c0b[tid] = c;
  }
  __syncthreads();

  const int wv = tid >> 6, lane = tid & 63;
  const int wave0 = blockIdx.x * 4 + wv;
  float* const hb = hbuf[wv];

  // phase-1 constants (persist across trips)
  const int j32 = lane & 31, vh = lane >> 5;
  float w1r[5];
#pragma unroll
  for (int i = 0; i < 5; ++i) w1r[i] = W1[i * 32 + j32];
  const float b1r = b1[j32];

  const int q = lane & 3, pp = lane >> 2;

  for (int grp = wave0; grp < ngroups; grp += totalWaves) {
    const int P0 = grp * 16;           // 16 pillars per wave per trip

    // ---- phase 1: layer1.  lane = (j32, voxel-half vh)
    {
      const float4* pv4 = (const float4*)pvox;
      const int vmax = 2 * U - 1;
#pragma unroll
      for (int v = 0; v < 16; ++v) {
        int vg = 2 * P0 + 16 * vh + v;
        vg = vg < vmax ? vg : vmax;
        float4 g1 = pv4[2 * vg];
        float4 g2 = pv4[2 * vg + 1];
        float h = b1r + g1.x * w1r[0] + g1.y * w1r[1] + g1.z * w1r[2] +
                  g1.w * w1r[3] + g2.x * w1r[4];
        // row = slot*16 + pillar-in-wave  (bank step 4 for phase-2 reads)
        const int row = (v & 1) * 16 + 8 * vh + (v >> 1);
        hb[row * 36 + j32] = fmaxf(h, 0.0f);
      }
    }
    drain_lds();

    // ---- phase 2: lane = (pillar pp, ch-quad q); channels 16q..16q+15
    const int pg = P0 + pp;
    const int pc = pg < U ? pg : (U - 1);
    const int cnt = unq_cnt[pc];
    const bool has2 = (cnt >= 2);
    const int* pvi = (const int*)pvox;
    const int b0 = pvi[(size_t)(2 * pc) * 8 + 5] & 31;
    const int b1raw = pvi[(size_t)(2 * pc + 1) * 8 + 5];
    const int b1e = has2 ? (b1raw & 31) : 64;

    // layer2
    float y0[16], y1[16];
    const float4* b2b4 = (const float4*)b2b;
#pragma unroll
    for (int kb = 0; kb < 4; ++kb) {
      float4 w = b2b4[q * 4 + kb];
      y0[4 * kb] = w.x; y0[4 * kb + 1] = w.y; y0[4 * kb + 2] = w.z; y0[4 * kb + 3] = w.w;
      y1[4 * kb] = w.x; y1[4 * kb + 1] = w.y; y1[4 * kb + 2] = w.z; y1[4 * kb + 3] = w.w;
    }
    const float4* hb4 = (const float4*)hb;
    const float4* w2b4 = (const float4*)w2b;
    // 2-deep read-ahead on h (rows pp and 16+pp, stride 36 floats = 9 f4)
    float4 h0c = hb4[pp * 9];
    float4 h1c = hb4[(16 + pp) * 9];
#pragma unroll
    for (int jb = 0; jb < 8; ++jb) {
      float4 h0n, h1n;
      if (jb < 7) {
        h0n = hb4[pp * 9 + jb + 1];
        h1n = hb4[(16 + pp) * 9 + jb + 1];
      }
      float h0a[4] = {h0c.x, h0c.y, h0c.z, h0c.w};
      float h1a[4] = {h1c.x, h1c.y, h1c.z, h1c.w};
#pragma unroll
      for (int jj = 0; jj < 4; ++jj) {
        const int j = 4 * jb + jj;
#pragma unroll
        for (int kb = 0; kb < 4; ++kb) {
          float4 w = w2b4[17 * j + 4 * q + kb];   // q-pairs 2-way: free
          y0[4 * kb]     += h0a[jj] * w.x; y0[4 * kb + 1] += h0a[jj] * w.y;
          y0[4 * kb + 2] += h0a[jj] * w.z; y0[4 * kb + 3] += h0a[jj] * w.w;
          y1[4 * kb]     += h1a[jj] * w.x; y1[4 * kb + 1] += h1a[jj] * w.y;
          y1[4 * kb + 2] += h1a[jj] * w.z; y1[4 * kb + 3] += h1a[jj] * w.w;
        }
      }
      h0c = h0n; h1c = h1n;
    }
#pragma unroll
    for (int k = 0; k < 16; ++k) y1[k] = has2 ? y1[k] : y0[k];

    // pooled stats + chMLP layer1 partials (thread-local over 16 ch)
    float ha[16] = {0}, hm[16] = {0};
    const float kf = has2 ? 30.0f : 31.0f;     // 32 - nocc
    const float inv32 = 1.0f / 32.0f;
    const float4* c04 = (const float4*)c0b;
    const float4* wc14 = (const float4*)wc1b;
#pragma unroll
    for (int kb = 0; kb < 4; ++kb) {
      float4 cq = c04[q * 4 + kb];
      float c0a[4] = {cq.x, cq.y, cq.z, cq.w};
#pragma unroll
      for (int i = 0; i < 4; ++i) {
        const int k = 4 * kb + i;
        const float c0v = c0a[i];
        const float sumy = y0[k] + (has2 ? y1[k] : 0.0f);
        const float avg = fmaf(c0v, kf, sumy) * inv32;
        const float mxv = fmaxf(fmaxf(y0[k], y1[k]), c0v);
#pragma unroll
        for (int jb = 0; jb < 4; ++jb) {
          float4 w = wc14[(4 * k + q) * 4 + jb];   // k-major: q 2-way, free
          ha[4 * jb]     += avg * w.x; ha[4 * jb + 1] += avg * w.y;
          ha[4 * jb + 2] += avg * w.z; ha[4 * jb + 3] += avg * w.w;
          hm[4 * jb]     += mxv * w.x; hm[4 * jb + 1] += mxv * w.y;
          hm[4 * jb + 2] += mxv * w.z; hm[4 * jb + 3] += mxv * w.w;
        }
      }
    }
    // quad-reduce partials, bias, relu, combine pools
    float g[16];
    const float4* bc14 = (const float4*)bc1b;
#pragma unroll
    for (int jb = 0; jb < 4; ++jb) {
      float4 bb = bc14[jb];
      float bba[4] = {bb.x, bb.y, bb.z, bb.w};
#pragma unroll
      for (int i = 0; i < 4; ++i) {
        const int j = 4 * jb + i;
        const float sa = qsum4(ha[j]) + bba[i];
        const float sm = qsum4(hm[j]) + bba[i];
        g[j] = fmaxf(sa, 0.0f) + fmaxf(sm, 0.0f);
      }
    }

    // chMLP layer2 -> attc; bin-column partial reductions
    float attc[16];
    float sc = 0.0f, mc = -3.0e38f;
    float sy0 = 0.0f, my0 = -3.0e38f, sy1 = 0.0f, my1 = -3.0e38f;
    const float4* wc24 = (const float4*)wc2b;
    const float4* bc24 = (const float4*)bc2b;
#pragma unroll
    for (int kb = 0; kb < 4; ++kb) {
      float4 cq = c04[q * 4 + kb];
      float4 bq = bc24[q * 4 + kb];
      float c0a[4] = {cq.x, cq.y, cq.z, cq.w};
      float b2a[4] = {bq.x, bq.y, bq.z, bq.w};
#pragma unroll
      for (int i = 0; i < 4; ++i) {
        const int k = 4 * kb + i;
        float pre = 2.0f * b2a[i];
#pragma unroll
        for (int jb = 0; jb < 4; ++jb) {
          float4 w = wc24[(4 * k + q) * 4 + jb];
          pre += g[4 * jb] * w.x + g[4 * jb + 1] * w.y +
                 g[4 * jb + 2] * w.z + g[4 * jb + 3] * w.w;
        }
        const float a = sgm(pre);
        attc[k] = a;
        const float pc0 = a * c0a[i], py0 = a * y0[k], py1 = a * y1[k];
        sc += pc0;  mc = fmaxf(mc, pc0);
        sy0 += py0; my0 = fmaxf(my0, py0);
        sy1 += py1; my1 = fmaxf(my1, py1);
      }
    }
    sc = qsum4(sc);   mc = qmax4(mc);
    sy0 = qsum4(sy0); my0 = qmax4(my0);
    sy1 = qsum4(sy1); my1 = qmax4(my1);

    // analytic conv over 32 bins, 8 bins per lane, quad-combined
    const float inv64 = 1.0f / 64.0f;
    const float Mn = sc * inv64, Mx = mc;
    const float dm0 = (sy0 - sc) * inv64, dx0 = my0 - mc;
    const float dm1 = (sy1 - sc) * inv64, dx1 = my1 - mc;
    const float bspr = bsp[0];
    const float2* ws2 = (const float2*)wsmx;
    const float2* wt2 = (const float2*)wtab;
    float maxE = -3.0e38f, minE = 3.0e38f, sv0 = -3.0e38f, sv1 = -3.0e38f;
#pragma unroll
    for (int k = 0; k < 8; ++k) {
      const int b = 8 * q + k;
      float2 ws = ws2[b];
      float acc = bspr + Mn * ws.x + Mx * ws.y;
      int k0 = b0 - b + 3;  k0 = ((unsigned)k0 <= 6u) ? k0 : 7;
      int k1 = b1e - b + 3; k1 = ((unsigned)k1 <= 6u) ? k1 : 7;
      float2 w0 = wt2[k0];
      float2 w1v = wt2[k1];
      acc += dm0 * w0.x + dx0 * w0.y + dm1 * w1v.x + dx1 * w1v.y;
      const bool o0 = (b == b0), o1 = (b == b1e);
      const bool oc = o0 || o1;
      maxE = fmaxf(maxE, oc ? -3.0e38f : acc);
      minE = fminf(minE, oc ?  3.0e38f : acc);
      sv0 = o0 ? acc : sv0;
      sv1 = o1 ? acc : sv1;
    }
    maxE = qmax4(maxE); minE = qmin4(minE);
    sv0 = qmax4(sv0);   sv1 = qmax4(sv1);
    const float sig0 = sgm(sv0);
    const float sig1 = has2 ? sgm(sv1) : sig0;
    const float sE = sgm(maxE), sI = sgm(minE);

    // epilogue: final max over bins, stores
    if (pg < U) {
      float4* ov = (float4*)(out + (size_t)pg * CO + 16 * q);
#pragma unroll
      for (int kb = 0; kb < 4; ++kb) {
        float4 cq = c04[q * 4 + kb];
        float c0a[4] = {cq.x, cq.y, cq.z, cq.w};
        float rr[4];
#pragma unroll
        for (int i = 0; i < 4; ++i) {
          const int k = 4 * kb + i;
          const float c0v = c0a[i];
          const float sel = (c0v >= 0.0f) ? sE : sI;
          const float m = fmaxf(fmaxf(y0[k] * sig0, y1[k] * sig1), c0v * sel);
          rr[i] = attc[k] * m;
        }
        float4 r; r.x = rr[0]; r.y = rr[1]; r.z = rr[2]; r.w = rr[3];
        ov[kb] = r;
      }
      if (q == 0) out[(size_t)U * CO + pg] = has2 ? 1.0f : 0.0f;
    }
    drain_lds();   // hbuf reused next trip: all reads done before rewrite
  }
}

extern "C" void kernel_launch(void* const* d_in, const int* in_sizes, int n_in,
                              void* d_out, int out_size, void* d_ws, size_t ws_size,
                              hipStream_t stream) {
  const float* vf      = (const float*)d_in[0];
  const int*   vcoord  = (const int*)d_in[1];
  // d_in[2] = unq_coords (unused: identity)
  const int*   unq_inv = (const int*)d_in[3];
  const int*   unq_cnt = (const int*)d_in[4];
  const float* W1  = (const float*)d_in[5];
  const float* b1  = (const float*)d_in[6];
  const float* W2  = (const float*)d_in[7];
  const float* b2  = (const float*)d_in[8];
  const float* Wc1 = (const float*)d_in[9];
  const float* bc1 = (const float*)d_in[10];
  const float* Wc2 = (const float*)d_in[11];
  const float* bc2 = (const float*)d_in[12];
  const float* Wsp = (const float*)d_in[13];
  const float* bsp = (const float*)d_in[14];

  const int N = in_sizes[3];   // voxels
  const int U = in_sizes[4];   // pillars

  float* pvox = (float*)d_ws;  // 2U records x 32B (6.4 MB @ U=100k)

  pack_kernel<<<(N + 255) / 256, 256, 0, stream>>>(vf, vcoord, unq_inv, pvox, N);

  const int ngroups = (U + 15) / 16;      // 16 pillars per wave-trip
  int blocks = 1024;                      // 4 blocks/CU resident (persistent)
  const int maxBlocks = (ngroups + 3) / 4;
  if (blocks > maxBlocks) blocks = maxBlocks;
  const int totalWaves = blocks * 4;
  cbam_kernel<<<blocks, 256, 0, stream>>>(
      pvox, unq_cnt, W1, b1, W2, b2, Wc1, bc1, Wc2, bc2, Wsp, bsp,
      (float*)d_out, U, ngroups, totalWaves);
}